// Round 18
// baseline (1100.094 us; speedup 1.0000x reference)
//
#include <hip/hip_runtime.h>
#include <hip/hip_bf16.h>

typedef __attribute__((ext_vector_type(8))) short bf16x8;
typedef __attribute__((ext_vector_type(4))) float f32x4;

#define MFMA16(a,b,c) __builtin_amdgcn_mfma_f32_16x16x32_bf16(a,b,c,0,0,0)

__device__ inline ushort f2bf(float f){
  union { float f; uint u; } v; v.f = f;
  uint r = v.u + 0x7FFFu + ((v.u >> 16) & 1u);
  return (ushort)(r >> 16);
}
__device__ inline float sigf(float x){ return 1.f/(1.f+__expf(-x)); }
__device__ inline float tanhf_(float x){ return 2.f/(1.f+__expf(-2.f*x)) - 1.f; }

__device__ inline void gload_lds16(const ushort* g, ushort* lds){
  __builtin_amdgcn_global_load_lds(
      (const __attribute__((address_space(1))) void*)g,
      (__attribute__((address_space(3))) void*)lds, 16, 0, 0);
}

// ---------------- weight fp32 -> bf16 conversion ----------------
__global__ void convert_weights(const float* __restrict__ s0, const float* __restrict__ s1,
                                const float* __restrict__ s2, const float* __restrict__ s3,
                                ushort* __restrict__ dst){
  size_t i4 = ((size_t)blockIdx.x*256 + threadIdx.x)*4;
  int tsel = (int)(i4 >> 21);
  const float* s = (tsel & 2) ? ((tsel & 1) ? s3 : s2) : ((tsel & 1) ? s1 : s0);
  size_t off = i4 & 2097151u;
  float4 v = *(const float4*)&s[off];
  ushort4 o; o.x=f2bf(v.x); o.y=f2bf(v.y); o.z=f2bf(v.z); o.w=f2bf(v.w);
  *(ushort4*)&dst[i4] = o;
}

// ---------------- embed ----------------
__global__ void embed_kernel(const float* __restrict__ obsVel, const float* __restrict__ mean,
                             const float* __restrict__ stdv, const float* __restrict__ encW,
                             const float* __restrict__ encb, ushort* __restrict__ embed){
  int idx = blockIdx.x*256 + threadIdx.x;   // < 32768*64
  int row = idx >> 6, c8 = (idx & 63) * 8;
  float x0 = (obsVel[row*2+0] - mean[0]) / stdv[0];
  float x1 = (obsVel[row*2+1] - mean[1]) / stdv[1];
  ushort o[8];
  #pragma unroll
  for (int j=0;j<8;j++){
    int col = c8 + j;
    o[j] = f2bf(x0*encW[col] + x1*encW[512+col] + encb[col]);
  }
  *(uint4*)&embed[(size_t)row*512 + c8] = *(const uint4*)o;
}

// ---------------- fused LSTM cell step: phase template @ 2-3 blocks/CU ----------------
// 256 thr = 4 waves (2M x 2N), wave tile 64 x 64 (4 gates x 16 cols -> gates
// in-lane, fused epilogue). Block tile 128 rows x (4 gates x 32 cols). BK=32.
// grid (16,32) = 512 blocks = 2/CU min (3/CU if VGPR<=168). A and B both
// LDS-staged via global_load_lds; 3 bufs x (8KB A + 8KB B) = 48 KB.
// Row-pair LDS packing (r4-proven 0-conflict): logical row r (64B, 4 chunks)
// at LDS row r&63 (128B, 8 slots), slot(r,c) = ((r>>6)*4+c) ^ (r&7).
// Phase per K-tile: {8 ds_read || 4 gload(kt+2) -> 16 MFMA (setprio) ->
// vmcnt(4) -> s_barrier}; vmcnt never 0 in main loop (depth-2).
// C/bias loaded in epilogue to cap VGPR (no r15-style spill).
#define NKT_SEG 16   // K=512 per segment / BK=32

__global__ __launch_bounds__(256, 2) void lstm_cell_kernel(
    const ushort* __restrict__ A0, int lda0,
    const ushort* __restrict__ A1, int lda1,
    const ushort* __restrict__ B0,
    const ushort* __restrict__ B1,
    const float*  __restrict__ bias,
    float* __restrict__ C,
    ushort* __restrict__ H0, int ldh0,
    ushort* __restrict__ H1, int ldh1,
    int nSeg, int czero)
{
  __shared__ ushort aL[3][4096];   // 64 LDS-rows x 64 ushort (128 B)
  __shared__ ushort bL[3][4096];
  const int tid = threadIdx.x;
  const int w = tid >> 6, lane = tid & 63;
  const int wr = w >> 1, wc = w & 1;
  const int bm = blockIdx.y * 128;
  const int bn = blockIdx.x * 32;            // gate-local col base

  f32x4 acc[4][4];   // [m][gate]
  #pragma unroll
  for (int m=0;m<4;m++)
    #pragma unroll
    for (int g=0;g<4;g++) acc[m][g] = (f32x4)0.f;

  // ---- staging addresses: 2 chunks/thread for A, 2 for B; inverse swizzle ----
  // chunk i -> LDS byte i*16; (rl=i>>3, s=i&7) -> x=s^(rl&7): r=(x>>2)*64+rl, c=x&3
  int arow[2], brow[2], chS[2], ldsO[2];
  #pragma unroll
  for (int p=0;p<2;p++){
    int i = p*256 + tid;
    int rl = i>>3, s = i&7, x = s ^ (rl&7);
    int r = ((x>>2)<<6) + rl;
    arow[p] = bm + r;
    brow[p] = ((r>>5)<<9) + bn + (r&31);   // flat weight row = gate*512 + bn + col
    chS[p]  = (x & 3) * 8;                  // src k-chunk offset (ushorts)
    ldsO[p] = (p*256 + (tid & ~63)) * 8;    // wave-uniform base (ushort units)
  }

  // ---- frag read offsets (ushort units) ----
  const int q = lane >> 4;
  int aOff[4], bOff[4];
  #pragma unroll
  for (int m=0;m<4;m++){
    int ra = wr*64 + m*16 + (lane&15);
    int slot = (((ra>>6)<<2) + q) ^ (ra&7);
    aOff[m] = (ra&63)*64 + slot*8;
  }
  #pragma unroll
  for (int g=0;g<4;g++){
    int rb = g*32 + wc*16 + (lane&15);
    int slot = (((rb>>6)<<2) + q) ^ (rb&7);
    bOff[g] = (rb&63)*64 + slot*8;
  }

  #define STAGE(bi, kt) do { \
    const ushort* Aseg_ = ((kt) < NKT_SEG) ? A0 : A1; \
    const int lda_ = ((kt) < NKT_SEG) ? lda0 : lda1; \
    const ushort* Bseg_ = ((kt) < NKT_SEG) ? B0 : B1; \
    const int k0_ = ((kt) & (NKT_SEG-1)) << 5; \
    gload_lds16(Aseg_ + (size_t)arow[0]*lda_ + k0_ + chS[0], &aL[bi][ldsO[0]]); \
    gload_lds16(Bseg_ + ((size_t)brow[0]<<9) + k0_ + chS[0], &bL[bi][ldsO[0]]); \
    gload_lds16(Aseg_ + (size_t)arow[1]*lda_ + k0_ + chS[1], &aL[bi][ldsO[1]]); \
    gload_lds16(Bseg_ + ((size_t)brow[1]<<9) + k0_ + chS[1], &bL[bi][ldsO[1]]); \
  } while(0)

  #define PHASE(bc, bs, kt, DOSTG, VMN) do { \
    bf16x8 aF[4], bF[4]; \
    _Pragma("unroll") \
    for (int m=0;m<4;m++) aF[m] = *(const bf16x8*)&aL[bc][aOff[m]]; \
    _Pragma("unroll") \
    for (int g=0;g<4;g++) bF[g] = *(const bf16x8*)&bL[bc][bOff[g]]; \
    if (DOSTG) STAGE(bs, (kt)+2); \
    __builtin_amdgcn_s_setprio(1); \
    _Pragma("unroll") \
    for (int m=0;m<4;m++) \
      _Pragma("unroll") \
      for (int g=0;g<4;g++) acc[m][g] = MFMA16(aF[m], bF[g], acc[m][g]); \
    __builtin_amdgcn_s_setprio(0); \
    asm volatile("s_waitcnt vmcnt(" #VMN ")" ::: "memory"); \
    __builtin_amdgcn_s_barrier(); \
    __builtin_amdgcn_sched_barrier(0); \
  } while(0)

  const int nkt = nSeg * NKT_SEG;   // 16 or 32
  int b0 = 0, b1 = 1, b2 = 2;

  // prologue: stage kt=0,1 (4 loads each); vmcnt(4) -> kt=0 landed
  STAGE(0, 0);
  STAGE(1, 1);
  asm volatile("s_waitcnt vmcnt(4)" ::: "memory");
  __builtin_amdgcn_s_barrier();
  __builtin_amdgcn_sched_barrier(0);

  for (int kt = 0; kt < nkt-2; ++kt){
    PHASE(b0, b2, kt, 1, 4);
    int t_ = b0; b0 = b1; b1 = b2; b2 = t_;
  }
  // kt = nkt-2: no staging; drain stage(nkt-1) fully
  PHASE(b0, b2, 0, 0, 0);
  { int t_ = b0; b0 = b1; b1 = b2; b2 = t_; }
  // kt = nkt-1: nothing outstanding
  PHASE(b0, b2, 0, 0, 0);

  #undef STAGE
  #undef PHASE

  // ---- epilogue: bias + gates, c update, h writes (loads here to cap VGPR) ----
  const int r0 = bm + wr*64 + ((lane>>4)<<2);
  const int ccol = bn + wc*16 + (lane&15);
  const float b_i = bias[ccol];
  const float b_f = bias[512+ccol];
  const float b_g = bias[1024+ccol];
  const float b_o = bias[1536+ccol];
  #pragma unroll
  for (int m=0;m<4;m++){
    #pragma unroll
    for (int reg=0;reg<4;reg++){
      const int row = r0 + m*16 + reg;
      float gi = acc[m][0][reg] + b_i;
      float gf = acc[m][1][reg] + b_f;
      float gg = acc[m][2][reg] + b_g;
      float go = acc[m][3][reg] + b_o;
      size_t cidx = (size_t)row*512 + ccol;
      float cv = czero ? 0.f : C[cidx];
      float cn = sigf(gf)*cv + sigf(gi)*tanhf_(gg);
      float hv = sigf(go)*tanhf_(cn);
      C[cidx] = cn;
      ushort hb = f2bf(hv);
      H0[(size_t)row*ldh0 + ccol] = hb;
      if (H1) H1[(size_t)row*ldh1 + ccol] = hb;
    }
  }
}

// ---------------- projection + cumsum ----------------
__global__ void final_kernel(const ushort* __restrict__ pred, const float* __restrict__ decW,
                             const float* __restrict__ decb, const float* __restrict__ mean,
                             const float* __restrict__ stdv, const float* __restrict__ obs,
                             float* __restrict__ out){
  int w = threadIdx.x >> 6, lane = threadIdx.x & 63;
  int b = blockIdx.x*4 + w;
  float w0[8], w1[8];
  #pragma unroll
  for (int j=0;j<8;j++){
    int k = lane*8 + j;
    w0[j] = decW[k*2+0];
    w1[j] = decW[k*2+1];
  }
  float cum0 = 0.f, cum1 = 0.f;
  float m0 = mean[0], m1 = mean[1], sv0 = stdv[0], sv1 = stdv[1];
  float o0 = obs[(b*8+7)*2+0], o1 = obs[(b*8+7)*2+1];
  float db0 = decb[0], db1 = decb[1];
  for (int t=0;t<12;t++){
    const uint4 q = *(const uint4*)&pred[((size_t)b*12+t)*512 + lane*8];
    uint u[4] = {q.x,q.y,q.z,q.w};
    float s0=0.f, s1=0.f;
    #pragma unroll
    for (int p=0;p<4;p++){
      float lo = __uint_as_float(u[p]<<16);
      float hi = __uint_as_float(u[p]&0xffff0000u);
      s0 += lo*w0[2*p] + hi*w0[2*p+1];
      s1 += lo*w1[2*p] + hi*w1[2*p+1];
    }
    #pragma unroll
    for (int off=32; off>0; off>>=1){ s0 += __shfl_down(s0, off); s1 += __shfl_down(s1, off); }
    if (lane==0){
      cum0 += (s0+db0)*sv0 + m0;
      cum1 += (s1+db1)*sv1 + m1;
      out[((size_t)b*12+t)*2+0] = cum0 + o0;
      out[((size_t)b*12+t)*2+1] = cum1 + o1;
    }
  }
}

extern "C" void kernel_launch(void* const* d_in, const int* in_sizes, int n_in,
                              void* d_out, int out_size, void* d_ws, size_t ws_size,
                              hipStream_t stream) {
  const float* obs      = (const float*)d_in[0];
  const float* obsVel   = (const float*)d_in[1];
  const float* mean     = (const float*)d_in[2];
  const float* stdv     = (const float*)d_in[3];
  const float* encW     = (const float*)d_in[5];
  const float* encb     = (const float*)d_in[6];
  const float* decW     = (const float*)d_in[7];
  const float* decb     = (const float*)d_in[8];
  const float* lstm_Wih = (const float*)d_in[9];
  const float* lstm_Whh = (const float*)d_in[10];
  const float* lstm_b   = (const float*)d_in[11];
  const float* cell_Wih = (const float*)d_in[12];
  const float* cell_Whh = (const float*)d_in[13];
  const float* cell_b   = (const float*)d_in[14];

  char* ws = (char*)d_ws;
  ushort* wbf   = (ushort*)ws;                       // 16 MB
  ushort* embed = (ushort*)(ws + (16ull<<20));       // 32 MB
  ushort* h0[2] = {(ushort*)(ws + (48ull<<20)), (ushort*)(ws + (52ull<<20))};
  ushort* h1[2] = {(ushort*)(ws + (56ull<<20)), (ushort*)(ws + (60ull<<20))};
  float*  c0    = (float*)(ws + (64ull<<20));
  float*  c1    = (float*)(ws + (72ull<<20));
  ushort* pred  = (ushort*)(ws + (80ull<<20));       // 48 MB

  ushort* w_lstm_ih = wbf;
  ushort* w_lstm_hh = wbf + 2097152;
  ushort* w_cell_ih = wbf + 4194304;
  ushort* w_cell_hh = wbf + 6291456;

  convert_weights<<<8192, 256, 0, stream>>>(lstm_Wih, lstm_Whh, cell_Wih, cell_Whh, wbf);
  embed_kernel<<<8192, 256, 0, stream>>>(obsVel, mean, stdv, encW, encb, embed);

  dim3 grid(16, 32);
  int cur0 = 0, cur1 = 0;
  for (int t=0;t<8;t++){
    int ns = (t==0) ? 1 : 2;
    int cz = (t==0) ? 1 : 0;
    lstm_cell_kernel<<<grid, 256, 0, stream>>>(embed + t*512, 4096, h0[cur0], 512,
        w_lstm_ih, w_lstm_hh, lstm_b, c0, h0[cur0^1], 512, (ushort*)nullptr, 0, ns, cz);
    lstm_cell_kernel<<<grid, 256, 0, stream>>>(h0[cur0^1], 512, h1[cur1], 512,
        w_lstm_ih + 1048576, w_lstm_hh + 1048576, lstm_b + 2048, c1, h1[cur1^1], 512,
        (t==7) ? pred : (ushort*)nullptr, 6144, ns, cz);
    cur0 ^= 1; cur1 ^= 1;
  }
  for (int s=1;s<12;s++){
    lstm_cell_kernel<<<grid, 256, 0, stream>>>(pred + (s-1)*512, 6144, h0[cur0], 512,
        w_cell_ih, w_cell_hh, cell_b, c0, h0[cur0^1], 512, (ushort*)nullptr, 0, 2, 0);
    lstm_cell_kernel<<<grid, 256, 0, stream>>>(h0[cur0^1], 512, h1[cur1], 512,
        w_cell_ih + 1048576, w_cell_hh + 1048576, cell_b + 2048, c1, h1[cur1^1], 512,
        pred + s*512, 6144, 2, 0);
    cur0 ^= 1; cur1 ^= 1;
  }
  final_kernel<<<1024, 256, 0, stream>>>(pred, decW, decb, mean, stdv, obs, (float*)d_out);
}

// Round 19
// 971.866 us; speedup vs baseline: 1.1319x; 1.1319x over previous
//
#include <hip/hip_runtime.h>
#include <hip/hip_bf16.h>

typedef __attribute__((ext_vector_type(8))) short bf16x8;
typedef __attribute__((ext_vector_type(4))) float f32x4;

#define MFMA16(a,b,c) __builtin_amdgcn_mfma_f32_16x16x32_bf16(a,b,c,0,0,0)

__device__ inline ushort f2bf(float f){
  union { float f; uint u; } v; v.f = f;
  uint r = v.u + 0x7FFFu + ((v.u >> 16) & 1u);
  return (ushort)(r >> 16);
}
__device__ inline float sigf(float x){ return 1.f/(1.f+__expf(-x)); }
__device__ inline float tanhf_(float x){ return 2.f/(1.f+__expf(-2.f*x)) - 1.f; }

__device__ inline void gload_lds16(const ushort* g, ushort* lds){
  __builtin_amdgcn_global_load_lds(
      (const __attribute__((address_space(1))) void*)g,
      (__attribute__((address_space(3))) void*)lds, 16, 0, 0);
}

// ---------------- prep: weight fp32->bf16 convert + embed, one dispatch ----------------
__global__ void prep_kernel(const float* __restrict__ s0, const float* __restrict__ s1,
                            const float* __restrict__ s2, const float* __restrict__ s3,
                            ushort* __restrict__ dst,
                            const float* __restrict__ obsVel, const float* __restrict__ mean,
                            const float* __restrict__ stdv, const float* __restrict__ encW,
                            const float* __restrict__ encb, ushort* __restrict__ embed){
  if (blockIdx.x < 8192){
    size_t i4 = ((size_t)blockIdx.x*256 + threadIdx.x)*4;
    int tsel = (int)(i4 >> 21);
    const float* s = (tsel & 2) ? ((tsel & 1) ? s3 : s2) : ((tsel & 1) ? s1 : s0);
    size_t off = i4 & 2097151u;
    float4 v = *(const float4*)&s[off];
    ushort4 o; o.x=f2bf(v.x); o.y=f2bf(v.y); o.z=f2bf(v.z); o.w=f2bf(v.w);
    *(ushort4*)&dst[i4] = o;
  } else {
    int idx = (blockIdx.x - 8192)*256 + threadIdx.x;   // < 32768*64
    int row = idx >> 6, c8 = (idx & 63) * 8;
    float x0 = (obsVel[row*2+0] - mean[0]) / stdv[0];
    float x1 = (obsVel[row*2+1] - mean[1]) / stdv[1];
    ushort o[8];
    #pragma unroll
    for (int j=0;j<8;j++){
      int col = c8 + j;
      o[j] = f2bf(x0*encW[col] + x1*encW[512+col] + encb[col]);
    }
    *(uint4*)&embed[(size_t)row*512 + c8] = *(const uint4*)o;
  }
}

// ---------------- fused LSTM cell step: r17 m201 phase-template (verbatim body) ----------------
// 512 thr = 8 waves (2 M-halves x 4 N-quarters), wave tile 64 x 64.
// Block tile 128 rows x (4 gates x 64 cols, gate-interleaved, gates in-lane).
// BK=64. A and B LDS-staged (global_load_lds), 3 bufs x 48 KB, depth-2.
// Two phases per K-tile with fine ds_read || stage interleave, lgkm partial
// waits, vmcnt(6) once per K-tile (never 0 in main loop), setprio on MFMA.
// Pair support: blockIdx.y < nyA -> cell A, else cell B (independent cells).
#define NKT_SEG 8   // K=512 per segment / BK=64

struct CellArgs {
  const ushort *A0, *A1, *B0, *B1;
  const float *bias;
  float *C;
  ushort *H0, *H1;
  int lda0, lda1, ldh1, nSeg, czero;
};

__global__ __launch_bounds__(512, 2) void lstm_cell_kernel(CellArgs cA, CellArgs cB, int nyA){
  __shared__ ushort aL [3][8192];    // A: 128 rows x 64 k bf16, swizzled
  __shared__ ushort bLs[3][16384];   // B: 256 rows x 64 k bf16, swizzled
  const bool isA = (int)blockIdx.y < nyA;
  const CellArgs P = isA ? cA : cB;
  const int by = isA ? blockIdx.y : (blockIdx.y - nyA);
  const int tid = threadIdx.x;       // 0..511
  const int w = tid >> 6, lane = tid & 63;
  const int wr = w >> 2, wc = w & 3;
  const int bm = by * 128;
  const int bn = blockIdx.x * 64;    // gate-local col base

  // ---- epilogue operand prefetch (oldest VMEM; drained by prologue wait) ----
  const int r0 = bm + wr*64 + ((lane>>4)<<2);
  const int ccol = bn + wc*16 + (lane&15);
  float br[4], creg[4][4];
  #pragma unroll
  for (int g=0;g<4;g++) br[g] = P.bias[g*512 + ccol];
  if (P.czero){
    #pragma unroll
    for (int m=0;m<4;m++)
      #pragma unroll
      for (int reg=0;reg<4;reg++) creg[m][reg] = 0.f;
  } else {
    #pragma unroll
    for (int m=0;m<4;m++)
      #pragma unroll
      for (int reg=0;reg<4;reg++)
        creg[m][reg] = P.C[(size_t)(r0 + m*16 + reg)*512 + ccol];
  }

  f32x4 acc[4][4];   // [m][gate]
  #pragma unroll
  for (int m=0;m<4;m++)
    #pragma unroll
    for (int g=0;g<4;g++) acc[m][g] = (f32x4)0.f;

  // ---- staging address precompute (inverse swizzle; linear LDS dest) ----
  int ar_[2], ac_[2], aO_[2];
  #pragma unroll
  for (int p=0;p<2;p++){
    int i = p*512 + tid;
    int r = i>>3, s = i&7;
    ar_[p] = r;  ac_[p] = s ^ (r&7);
    aO_[p] = (p*512 + (tid & ~63)) * 8;
  }
  int bfr_[4], bc_[4], bO_[4];
  #pragma unroll
  for (int p=0;p<4;p++){
    int i = p*512 + tid;
    int r = i>>3, s = i&7;
    bfr_[p] = ((r>>6)<<9) + bn + (r&63);   // flat weight row = gate*512+bn+col
    bc_[p]  = s ^ (r&7);
    bO_[p]  = (p*512 + (tid & ~63)) * 8;
  }

  // ---- frag read offsets (ushort units); kk=1 -> ^32 ----
  int aOff[4], bOff[4];
  #pragma unroll
  for (int m=0;m<4;m++){
    int ra = wr*64 + m*16 + (lane&15);
    aOff[m] = ra*64 + (((lane>>4)) ^ (ra&7))*8;
  }
  #pragma unroll
  for (int n=0;n<4;n++){
    int rb = n*64 + wc*16 + (lane&15);
    bOff[n] = rb*64 + (((lane>>4)) ^ (rb&7))*8;
  }

  #define STAGE_A(bi, kt) do { \
    const ushort* Aseg_ = ((kt) < NKT_SEG) ? P.A0 : P.A1; \
    const int lda_ = ((kt) < NKT_SEG) ? P.lda0 : P.lda1; \
    const int k0_ = ((kt) & 7) << 6; \
    gload_lds16(Aseg_ + (size_t)(bm + ar_[0])*lda_ + k0_ + ac_[0]*8, &aL[bi][aO_[0]]); \
    gload_lds16(Aseg_ + (size_t)(bm + ar_[1])*lda_ + k0_ + ac_[1]*8, &aL[bi][aO_[1]]); \
  } while(0)

  #define STAGE_B0(bi, kt) do { \
    const ushort* Bseg_ = ((kt) < NKT_SEG) ? P.B0 : P.B1; \
    const int k0_ = ((kt) & 7) << 6; \
    gload_lds16(Bseg_ + (size_t)bfr_[0]*512 + k0_ + bc_[0]*8, &bLs[bi][bO_[0]]); \
    gload_lds16(Bseg_ + (size_t)bfr_[1]*512 + k0_ + bc_[1]*8, &bLs[bi][bO_[1]]); \
  } while(0)

  #define STAGE_B1(bi, kt) do { \
    const ushort* Bseg_ = ((kt) < NKT_SEG) ? P.B0 : P.B1; \
    const int k0_ = ((kt) & 7) << 6; \
    gload_lds16(Bseg_ + (size_t)bfr_[2]*512 + k0_ + bc_[2]*8, &bLs[bi][bO_[2]]); \
    gload_lds16(Bseg_ + (size_t)bfr_[3]*512 + k0_ + bc_[3]*8, &bLs[bi][bO_[3]]); \
  } while(0)

  // Phase 1: read A (8) + B n0-1 (4); stage A + B-half0 of kt+2; 16 MFMA (n0,1)
  #define P1BODY(bic, bis, ktv, DOSTG) do { \
    _Pragma("unroll") \
    for (int m=0;m<4;m++){ \
      aF[m][0] = *(const bf16x8*)&aL[bic][aOff[m]]; \
      aF[m][1] = *(const bf16x8*)&aL[bic][aOff[m]^32]; \
    } \
    _Pragma("unroll") \
    for (int n=0;n<2;n++){ \
      bF[n][0] = *(const bf16x8*)&bLs[bic][bOff[n]]; \
      bF[n][1] = *(const bf16x8*)&bLs[bic][bOff[n]^32]; \
    } \
    if (DOSTG){ STAGE_A(bis, (ktv)+2); STAGE_B0(bis, (ktv)+2); } \
    asm volatile("s_waitcnt lgkmcnt(8)" ::: "memory"); \
    __builtin_amdgcn_s_barrier(); \
    asm volatile("s_waitcnt lgkmcnt(0)" ::: "memory"); \
    __builtin_amdgcn_sched_barrier(0); \
    __builtin_amdgcn_s_setprio(1); \
    _Pragma("unroll") \
    for (int kk=0;kk<2;kk++) \
      _Pragma("unroll") \
      for (int n=0;n<2;n++) \
        _Pragma("unroll") \
        for (int m=0;m<4;m++) \
          acc[m][n] = MFMA16(aF[m][kk], bF[n][kk], acc[m][n]); \
    __builtin_amdgcn_s_setprio(0); \
    __builtin_amdgcn_s_barrier(); \
  } while(0)

  // Phase 2: read B n2-3 (4); stage B-half1 of kt+2; vmcnt(VMN); 16 MFMA (n2,3)
  #define P2BODY(bic, bis, ktv, DOSTG, VMN) do { \
    _Pragma("unroll") \
    for (int n=0;n<2;n++){ \
      bF[n][0] = *(const bf16x8*)&bLs[bic][bOff[n+2]]; \
      bF[n][1] = *(const bf16x8*)&bLs[bic][bOff[n+2]^32]; \
    } \
    if (DOSTG){ STAGE_B1(bis, (ktv)+2); } \
    asm volatile("s_waitcnt vmcnt(" #VMN ")" ::: "memory"); \
    __builtin_amdgcn_s_barrier(); \
    asm volatile("s_waitcnt lgkmcnt(0)" ::: "memory"); \
    __builtin_amdgcn_sched_barrier(0); \
    __builtin_amdgcn_s_setprio(1); \
    _Pragma("unroll") \
    for (int kk=0;kk<2;kk++) \
      _Pragma("unroll") \
      for (int n=0;n<2;n++) \
        _Pragma("unroll") \
        for (int m=0;m<4;m++) \
          acc[m][n+2] = MFMA16(aF[m][kk], bF[n][kk], acc[m][n+2]); \
    __builtin_amdgcn_s_setprio(0); \
    __builtin_amdgcn_s_barrier(); \
  } while(0)

  const int nkt = P.nSeg * NKT_SEG;   // 8 or 16
  int b0 = 0, b1 = 1, b2 = 2;
  bf16x8 aF[4][2], bF[2][2];

  // prologue: stage kt=0 and kt=1 (6 loads each); wait kt=0 landed (6 newer)
  STAGE_A(0, 0); STAGE_B0(0, 0); STAGE_B1(0, 0);
  STAGE_A(1, 1); STAGE_B0(1, 1); STAGE_B1(1, 1);
  asm volatile("s_waitcnt vmcnt(6)" ::: "memory");
  __builtin_amdgcn_s_barrier();

  for (int kt = 0; kt < nkt-2; ++kt){
    P1BODY(b0, b2, kt, 1);
    P2BODY(b0, b2, kt, 1, 6);
    int t_ = b0; b0 = b1; b1 = b2; b2 = t_;
  }
  // kt = nkt-2: no staging; drain last tile's loads (issued one iter ago)
  P1BODY(b0, b2, 0, 0);
  P2BODY(b0, b2, 0, 0, 0);
  { int t_ = b0; b0 = b1; b1 = b2; b2 = t_; }
  // kt = nkt-1: no staging, nothing outstanding
  P1BODY(b0, b2, 0, 0);
  P2BODY(b0, b2, 0, 0, 0);

  #undef STAGE_A
  #undef STAGE_B0
  #undef STAGE_B1
  #undef P1BODY
  #undef P2BODY

  // ---- epilogue: bias + gates, c update, h writes (gates in-lane) ----
  #pragma unroll
  for (int m=0;m<4;m++){
    #pragma unroll
    for (int reg=0;reg<4;reg++){
      const int row = r0 + m*16 + reg;
      float gi = acc[m][0][reg] + br[0];
      float gf = acc[m][1][reg] + br[1];
      float gg = acc[m][2][reg] + br[2];
      float go = acc[m][3][reg] + br[3];
      float cn = sigf(gf)*creg[m][reg] + sigf(gi)*tanhf_(gg);
      float hv = sigf(go)*tanhf_(cn);
      P.C[(size_t)row*512 + ccol] = cn;
      ushort hb = f2bf(hv);
      P.H0[(size_t)row*512 + ccol] = hb;
      if (P.H1) P.H1[(size_t)row*P.ldh1 + ccol] = hb;
    }
  }
}

// ---------------- projection + cumsum ----------------
__global__ void final_kernel(const ushort* __restrict__ pred, const float* __restrict__ decW,
                             const float* __restrict__ decb, const float* __restrict__ mean,
                             const float* __restrict__ stdv, const float* __restrict__ obs,
                             float* __restrict__ out){
  int w = threadIdx.x >> 6, lane = threadIdx.x & 63;
  int b = blockIdx.x*4 + w;
  float w0[8], w1[8];
  #pragma unroll
  for (int j=0;j<8;j++){
    int k = lane*8 + j;
    w0[j] = decW[k*2+0];
    w1[j] = decW[k*2+1];
  }
  float cum0 = 0.f, cum1 = 0.f;
  float m0 = mean[0], m1 = mean[1], sv0 = stdv[0], sv1 = stdv[1];
  float o0 = obs[(b*8+7)*2+0], o1 = obs[(b*8+7)*2+1];
  float db0 = decb[0], db1 = decb[1];
  for (int t=0;t<12;t++){
    const uint4 q = *(const uint4*)&pred[((size_t)b*12+t)*512 + lane*8];
    uint u[4] = {q.x,q.y,q.z,q.w};
    float s0=0.f, s1=0.f;
    #pragma unroll
    for (int p=0;p<4;p++){
      float lo = __uint_as_float(u[p]<<16);
      float hi = __uint_as_float(u[p]&0xffff0000u);
      s0 += lo*w0[2*p] + hi*w0[2*p+1];
      s1 += lo*w1[2*p] + hi*w1[2*p+1];
    }
    #pragma unroll
    for (int off=32; off>0; off>>=1){ s0 += __shfl_down(s0, off); s1 += __shfl_down(s1, off); }
    if (lane==0){
      cum0 += (s0+db0)*sv0 + m0;
      cum1 += (s1+db1)*sv1 + m1;
      out[((size_t)b*12+t)*2+0] = cum0 + o0;
      out[((size_t)b*12+t)*2+1] = cum1 + o1;
    }
  }
}

extern "C" void kernel_launch(void* const* d_in, const int* in_sizes, int n_in,
                              void* d_out, int out_size, void* d_ws, size_t ws_size,
                              hipStream_t stream) {
  const float* obs      = (const float*)d_in[0];
  const float* obsVel   = (const float*)d_in[1];
  const float* mean     = (const float*)d_in[2];
  const float* stdv     = (const float*)d_in[3];
  const float* encW     = (const float*)d_in[5];
  const float* encb     = (const float*)d_in[6];
  const float* decW     = (const float*)d_in[7];
  const float* decb     = (const float*)d_in[8];
  const float* lstm_Wih = (const float*)d_in[9];
  const float* lstm_Whh = (const float*)d_in[10];
  const float* lstm_b   = (const float*)d_in[11];
  const float* cell_Wih = (const float*)d_in[12];
  const float* cell_Whh = (const float*)d_in[13];
  const float* cell_b   = (const float*)d_in[14];

  char* ws = (char*)d_ws;
  ushort* wbf   = (ushort*)ws;                       // 16 MB
  ushort* embed = (ushort*)(ws + (16ull<<20));       // 32 MB
  ushort* h0buf[2] = {(ushort*)(ws + (48ull<<20)), (ushort*)(ws + (52ull<<20))};
  ushort* h1buf[2] = {(ushort*)(ws + (56ull<<20)), (ushort*)(ws + (60ull<<20))};
  float*  c0    = (float*)(ws + (64ull<<20));
  float*  c1    = (float*)(ws + (72ull<<20));
  ushort* pred  = (ushort*)(ws + (80ull<<20));       // 48 MB

  const ushort* wl_ih = wbf;
  const ushort* wl_hh = wbf + 2097152;
  const ushort* wc_ih = wbf + 4194304;
  const ushort* wc_hh = wbf + 6291456;

  prep_kernel<<<16384, 256, 0, stream>>>(lstm_Wih, lstm_Whh, cell_Wih, cell_Whh, wbf,
                                         obsVel, mean, stdv, encW, encb, embed);

  // Per-step cell args. Slot convention: h after step t lives in buf[(t+1)&1].
  CellArgs L0[19], L1[19];
  for (int t=0; t<19; ++t){
    const bool enc = t < 8;
    L0[t].A0   = enc ? embed + t*512 : pred + (t-8)*512;
    L0[t].lda0 = enc ? 4096 : 6144;
    L0[t].A1   = h0buf[t&1];  L0[t].lda1 = 512;
    L0[t].B0   = enc ? wl_ih : wc_ih;
    L0[t].B1   = enc ? wl_hh : wc_hh;
    L0[t].bias = enc ? lstm_b : cell_b;
    L0[t].C    = c0;
    L0[t].H0   = h0buf[(t+1)&1];
    L0[t].H1   = nullptr;  L0[t].ldh1 = 0;
    L0[t].nSeg = (t==0) ? 1 : 2;
    L0[t].czero= (t==0) ? 1 : 0;

    L1[t].A0   = h0buf[(t+1)&1];  L1[t].lda0 = 512;
    L1[t].A1   = h1buf[t&1];      L1[t].lda1 = 512;
    L1[t].B0   = (enc ? wl_ih : wc_ih) + 1048576;
    L1[t].B1   = (enc ? wl_hh : wc_hh) + 1048576;
    L1[t].bias = (enc ? lstm_b : cell_b) + 2048;
    L1[t].C    = c1;
    L1[t].H0   = h1buf[(t+1)&1];
    L1[t].H1   = enc ? (t==7 ? pred : nullptr) : pred + (t-7)*512;
    L1[t].ldh1 = 6144;
    L1[t].nSeg = (t==0) ? 1 : 2;
    L1[t].czero= (t==0) ? 1 : 0;
  }

  // encoder: L0(0); then pairs {L0(t), L1(t-1)} (race-free: disjoint h-slots);
  // then L1(7). decoder: strictly sequential (true dependency through h1/pred).
  lstm_cell_kernel<<<dim3(8,32), 512, 0, stream>>>(L0[0], L0[0], 32);
  for (int t=1; t<8; ++t)
    lstm_cell_kernel<<<dim3(8,64), 512, 0, stream>>>(L0[t], L1[t-1], 32);
  lstm_cell_kernel<<<dim3(8,32), 512, 0, stream>>>(L1[7], L1[7], 32);
  for (int t=8; t<19; ++t){
    lstm_cell_kernel<<<dim3(8,32), 512, 0, stream>>>(L0[t], L0[t], 32);
    lstm_cell_kernel<<<dim3(8,32), 512, 0, stream>>>(L1[t], L1[t], 32);
  }

  final_kernel<<<1024, 256, 0, stream>>>(pred, decW, decb, mean, stdv, obs, (float*)d_out);
}